// Round 1
// baseline (1348.864 us; speedup 1.0000x reference)
//
#include <hip/hip_runtime.h>

// SGCNet: h=A^2 x; BN(hW1+b1); h=A^2 h; BN(hW2+b2); out = h W3 + b3
// A = norm-weighted adjacency (pull form by dest/col). All fp32.

#define WAVE 64

static inline size_t align256(size_t x) { return (x + 255) & ~(size_t)255; }

// ---------------- CSR build ----------------

__global__ void count_kernel(const int* __restrict__ row, const int* __restrict__ col,
                             int* __restrict__ cnt_row, int* __restrict__ cnt_col, int E) {
    int e = blockIdx.x * blockDim.x + threadIdx.x;
    if (e < E) {
        atomicAdd(&cnt_row[row[e]], 1);
        atomicAdd(&cnt_col[col[e]], 1);
    }
}

__global__ void dis_kernel(const int* __restrict__ cnt_row, float* __restrict__ dis, int n) {
    int i = blockIdx.x * blockDim.x + threadIdx.x;
    if (i < n) {
        int d = cnt_row[i];
        dis[i] = d > 0 ? rsqrtf((float)d) : 0.f;
    }
}

// 3-phase exclusive scan of cnt_col -> col_ptr.  CHUNK=2048 per block.
__global__ void scan1_kernel(const int* __restrict__ cnt, int n, int* __restrict__ bsum) {
    __shared__ int sh[256];
    int base = blockIdx.x * 2048 + threadIdx.x * 8;
    int s = 0;
#pragma unroll
    for (int i = 0; i < 8; ++i) { int idx = base + i; if (idx < n) s += cnt[idx]; }
    sh[threadIdx.x] = s;
    __syncthreads();
    for (int off = 128; off > 0; off >>= 1) {
        if (threadIdx.x < off) sh[threadIdx.x] += sh[threadIdx.x + off];
        __syncthreads();
    }
    if (threadIdx.x == 0) bsum[blockIdx.x] = sh[0];
}

__global__ void scan2_kernel(int* __restrict__ bsum, int nb, int* __restrict__ col_ptr, int n) {
    if (threadIdx.x == 0) {
        int run = 0;
        for (int i = 0; i < nb; ++i) { int v = bsum[i]; bsum[i] = run; run += v; }
        col_ptr[n] = run;
    }
}

__global__ void scan3_kernel(const int* __restrict__ cnt, int n, const int* __restrict__ bsum,
                             int* __restrict__ col_ptr) {
    __shared__ int sh[256];
    int base = blockIdx.x * 2048 + threadIdx.x * 8;
    int v[8];
    int s = 0;
#pragma unroll
    for (int i = 0; i < 8; ++i) {
        int idx = base + i;
        v[i] = (idx < n) ? cnt[idx] : 0;
        s += v[i];
    }
    sh[threadIdx.x] = s;
    __syncthreads();
    for (int off = 1; off < 256; off <<= 1) {
        int t = (threadIdx.x >= off) ? sh[threadIdx.x - off] : 0;
        __syncthreads();
        sh[threadIdx.x] += t;
        __syncthreads();
    }
    int run = bsum[blockIdx.x] + sh[threadIdx.x] - s;  // exclusive prefix
#pragma unroll
    for (int i = 0; i < 8; ++i) {
        int idx = base + i;
        if (idx < n) col_ptr[idx] = run;
        run += v[i];
    }
}

__global__ void fill_kernel(const int* __restrict__ row, const int* __restrict__ col,
                            const float* __restrict__ dis, const int* __restrict__ col_ptr,
                            int* __restrict__ fcnt, int* __restrict__ csr_row,
                            float* __restrict__ csr_norm, int E) {
    int e = blockIdx.x * blockDim.x + threadIdx.x;
    if (e < E) {
        int r = row[e], c = col[e];
        int pos = col_ptr[c] + atomicAdd(&fcnt[c], 1);
        csr_row[pos] = r;
        csr_norm[pos] = dis[r] * dis[c];
    }
}

// ---------------- SpMM (pull, one wave per dest node, float2/lane) ----------------

template <bool AFF>
__global__ void spmm_kernel(const int* __restrict__ col_ptr, const int* __restrict__ csr_row,
                            const float* __restrict__ csr_norm, const float* __restrict__ h_in,
                            const float* __restrict__ scale, const float* __restrict__ shift,
                            float* __restrict__ h_out, int n) {
    int gw = (blockIdx.x * blockDim.x + threadIdx.x) >> 6;  // wave id == dest node
    int lane = threadIdx.x & 63;
    if (gw >= n) return;
    int beg = col_ptr[gw], end = col_ptr[gw + 1];
    float2 acc = {0.f, 0.f};
    float2 sc, sh;
    if (AFF) {
        sc = ((const float2*)scale)[lane];
        sh = ((const float2*)shift)[lane];
    }
    for (int j = beg; j < end; ++j) {
        int src = csr_row[j];
        float w = csr_norm[j];
        float2 v = ((const float2*)(h_in + (size_t)src * 128))[lane];
        if (AFF) {
            v.x = sc.x * v.x + sh.x;
            v.y = sc.y * v.y + sh.y;
        }
        acc.x += w * v.x;
        acc.y += w * v.y;
    }
    ((float2*)(h_out + (size_t)gw * 128))[lane] = acc;
}

// ---------------- GEMM  Y[n,DO] = X[n,128] @ W[128,DO] + b ----------------

template <int DO>
__global__ void gemm_kernel(const float* __restrict__ X, const float* __restrict__ W,
                            const float* __restrict__ bias, float* __restrict__ Y, int n) {
    __shared__ float Ws[128 * DO];
    for (int i = threadIdx.x; i < 128 * DO; i += blockDim.x) Ws[i] = W[i];
    __syncthreads();
    constexpr int CG = DO / 4;       // float4 col-groups
    constexpr int RPB = 256 / CG;    // rows per block-iteration
    int cg = threadIdx.x % CG, rs = threadIdx.x / CG;
    float4 b4 = ((const float4*)bias)[cg];
    for (int r = blockIdx.x * RPB + rs; r < n; r += gridDim.x * RPB) {
        const float* xr = X + (size_t)r * 128;
        float4 acc = b4;
#pragma unroll 8
        for (int k = 0; k < 128; ++k) {
            float xv = xr[k];
            float4 w = ((const float4*)(Ws + k * DO))[cg];
            acc.x += xv * w.x;
            acc.y += xv * w.y;
            acc.z += xv * w.z;
            acc.w += xv * w.w;
        }
        ((float4*)(Y + (size_t)r * DO))[cg] = acc;
    }
}

// ---------------- BN stats / finalize / W3 fold ----------------

__global__ void stats_kernel(const float* __restrict__ Y, int n, float* __restrict__ gsum,
                             float* __restrict__ gsq) {
    __shared__ float s_sum[256], s_sq[256];
    int c = threadIdx.x & 127;
    int half = threadIdx.x >> 7;
    float sum = 0.f, sq = 0.f;
    for (int r = blockIdx.x * 2 + half; r < n; r += gridDim.x * 2) {
        float v = Y[(size_t)r * 128 + c];
        sum += v;
        sq += v * v;
    }
    s_sum[threadIdx.x] = sum;
    s_sq[threadIdx.x] = sq;
    __syncthreads();
    if (half == 0) {
        atomicAdd(&gsum[c], s_sum[c] + s_sum[c + 128]);
        atomicAdd(&gsq[c], s_sq[c] + s_sq[c + 128]);
    }
}

__global__ void bn_final_kernel(const float* __restrict__ gsum, const float* __restrict__ gsq,
                                const float* __restrict__ gamma, const float* __restrict__ beta,
                                int n, float* __restrict__ scale, float* __restrict__ shift) {
    int c = threadIdx.x;
    if (c < 128) {
        float fn = (float)n;
        float mu = gsum[c] / fn;
        float var = gsq[c] / fn - mu * mu;
        float inv = rsqrtf(var + 1e-5f);
        float sc = gamma[c] * inv;
        scale[c] = sc;
        shift[c] = beta[c] - sc * mu;
    }
}

// W3f[k][c] = scale2[k]*W3[k][c];  b3f[c] = b3[c] + sum_k shift2[k]*W3[k][c]
__global__ void fold_w3_kernel(const float* __restrict__ W3, const float* __restrict__ b3,
                               const float* __restrict__ scale, const float* __restrict__ shift,
                               float* __restrict__ W3f, float* __restrict__ b3f) {
    int c = threadIdx.x;
    if (c < 64) {
        float acc = b3[c];
        for (int k = 0; k < 128; ++k) {
            float w = W3[k * 64 + c];
            W3f[k * 64 + c] = scale[k] * w;
            acc += shift[k] * w;
        }
        b3f[c] = acc;
    }
}

// ---------------- launch ----------------

extern "C" void kernel_launch(void* const* d_in, const int* in_sizes, int n_in,
                              void* d_out, int out_size, void* d_ws, size_t ws_size,
                              hipStream_t stream) {
    const float* x = (const float*)d_in[0];
    const int* edge = (const int*)d_in[1];
    const float* W1 = (const float*)d_in[2];
    const float* b1 = (const float*)d_in[3];
    const float* g1 = (const float*)d_in[4];
    const float* be1 = (const float*)d_in[5];
    const float* W2 = (const float*)d_in[6];
    const float* b2 = (const float*)d_in[7];
    const float* g2 = (const float*)d_in[8];
    const float* be2 = (const float*)d_in[9];
    const float* W3 = (const float*)d_in[10];
    const float* b3 = (const float*)d_in[11];
    float* out = (float*)d_out;

    const int N = in_sizes[0] / 128;
    const int E = in_sizes[1] / 2;
    const int* erow = edge;
    const int* ecol = edge + E;

    // workspace carve
    char* p = (char*)d_ws;
    size_t off = 0;
    auto carve = [&](size_t bytes) {
        void* r = p + off;
        off += align256(bytes);
        return r;
    };
    float* bufA = (float*)carve((size_t)N * 128 * 4);
    float* bufB = (float*)carve((size_t)N * 128 * 4);
    int* csr_row = (int*)carve((size_t)E * 4);
    float* csr_norm = (float*)carve((size_t)E * 4);
    int* col_ptr = (int*)carve((size_t)(N + 1) * 4);
    // three contiguous zero-init int arrays (cnt_row, cnt_col, fcnt)
    size_t cnt_bytes = align256((size_t)N * 4);
    char* cnt_base = (char*)carve(3 * cnt_bytes);
    int* cnt_row = (int*)cnt_base;
    int* cnt_col = (int*)(cnt_base + cnt_bytes);
    int* fcnt = (int*)(cnt_base + 2 * cnt_bytes);
    float* dis = (float*)carve((size_t)N * 4);
    int* bsum = (int*)carve(4096);
    float* gsum = (float*)carve(512);   // gsum+gsq contiguous (1KB memset)
    float* gsq = (float*)(gsum + 128);
    float* scale1 = (float*)carve(512);
    float* shift1 = (float*)carve(512);
    float* scale2 = (float*)carve(512);
    float* shift2 = (float*)carve(512);
    float* W3f = (float*)carve(128 * 64 * 4);
    float* b3f = (float*)carve(256);
    (void)ws_size;

    const int TB = 256;
    const int gE = (E + TB - 1) / TB;
    const int gN = (N + TB - 1) / TB;
    const int NBLK = (N + 2047) / 2048;
    const int gSp = (N + 3) / 4;  // 4 waves (nodes) per 256-thr block

    // --- graph structure (rebuilt every call: launch must be stateless) ---
    hipMemsetAsync(cnt_base, 0, 3 * cnt_bytes, stream);
    count_kernel<<<gE, TB, 0, stream>>>(erow, ecol, cnt_row, cnt_col, E);
    dis_kernel<<<gN, TB, 0, stream>>>(cnt_row, dis, N);
    scan1_kernel<<<NBLK, TB, 0, stream>>>(cnt_col, N, bsum);
    scan2_kernel<<<1, 64, 0, stream>>>(bsum, NBLK, col_ptr, N);
    scan3_kernel<<<NBLK, TB, 0, stream>>>(cnt_col, N, bsum, col_ptr);
    fill_kernel<<<gE, TB, 0, stream>>>(erow, ecol, dis, col_ptr, fcnt, csr_row, csr_norm, E);

    // --- h = A^2 x ---
    spmm_kernel<false><<<gSp, TB, 0, stream>>>(col_ptr, csr_row, csr_norm, x, nullptr, nullptr, bufA, N);
    spmm_kernel<false><<<gSp, TB, 0, stream>>>(col_ptr, csr_row, csr_norm, bufA, nullptr, nullptr, bufB, N);

    // --- Y1 = h W1 + b1 ; BN1 stats ---
    gemm_kernel<128><<<2500, TB, 0, stream>>>(bufB, W1, b1, bufA, N);
    hipMemsetAsync(gsum, 0, 1024, stream);
    stats_kernel<<<256, TB, 0, stream>>>(bufA, N, gsum, gsq);
    bn_final_kernel<<<1, 128, 0, stream>>>(gsum, gsq, g1, be1, N, scale1, shift1);

    // --- h = A^2 BN1(Y1)  (affine fused into first gather) ---
    spmm_kernel<true><<<gSp, TB, 0, stream>>>(col_ptr, csr_row, csr_norm, bufA, scale1, shift1, bufB, N);
    spmm_kernel<false><<<gSp, TB, 0, stream>>>(col_ptr, csr_row, csr_norm, bufB, nullptr, nullptr, bufA, N);

    // --- Y2 = h W2 + b2 ; BN2 stats ---
    gemm_kernel<128><<<2500, TB, 0, stream>>>(bufA, W2, b2, bufB, N);
    hipMemsetAsync(gsum, 0, 1024, stream);
    stats_kernel<<<256, TB, 0, stream>>>(bufB, N, gsum, gsq);
    bn_final_kernel<<<1, 128, 0, stream>>>(gsum, gsq, g2, be2, N, scale2, shift2);

    // --- out = BN2(Y2) W3 + b3, BN2 folded into W3/b3 ---
    fold_w3_kernel<<<1, 64, 0, stream>>>(W3, b3, scale2, shift2, W3f, b3f);
    gemm_kernel<64><<<2500, TB, 0, stream>>>(bufB, W3f, b3f, out, N);
}

// Round 2
// 973.746 us; speedup vs baseline: 1.3852x; 1.3852x over previous
//
#include <hip/hip_runtime.h>

// SGCNet bf16 pipeline: CSR build -> spmm(bf16 gather, fp32 acc) x4
// -> MFMA bf16 GEMMs with BN folding.  Output fp32.

typedef __attribute__((ext_vector_type(8))) short bf16x8;
typedef __attribute__((ext_vector_type(4))) float f32x4;

static inline size_t align256(size_t x) { return (x + 255) & ~(size_t)255; }

__device__ inline unsigned short bf16rn(float f) {
    unsigned int u = __builtin_bit_cast(unsigned int, f);
    u += 0x7fffu + ((u >> 16) & 1u);
    return (unsigned short)(u >> 16);
}
__device__ inline float bflo(unsigned int u) { return __builtin_bit_cast(float, u << 16); }
__device__ inline float bfhi(unsigned int u) { return __builtin_bit_cast(float, u & 0xffff0000u); }
__device__ inline unsigned int packbf2(float a, float b) {
    return (unsigned int)bf16rn(a) | ((unsigned int)bf16rn(b) << 16);
}

// ---------------- CSR build ----------------

__global__ void count_kernel(const int* __restrict__ row, const int* __restrict__ col,
                             int* __restrict__ cnt_row, int* __restrict__ cnt_col, int E) {
    int e = blockIdx.x * blockDim.x + threadIdx.x;
    if (e < E) {
        atomicAdd(&cnt_row[row[e]], 1);
        atomicAdd(&cnt_col[col[e]], 1);
    }
}

__global__ void dis_kernel(const int* __restrict__ cnt_row, float* __restrict__ dis, int n) {
    int i = blockIdx.x * blockDim.x + threadIdx.x;
    if (i < n) {
        int d = cnt_row[i];
        dis[i] = d > 0 ? rsqrtf((float)d) : 0.f;
    }
}

__global__ void scan1_kernel(const int* __restrict__ cnt, int n, int* __restrict__ bsum) {
    __shared__ int sh[256];
    int base = blockIdx.x * 2048 + threadIdx.x * 8;
    int s = 0;
#pragma unroll
    for (int i = 0; i < 8; ++i) { int idx = base + i; if (idx < n) s += cnt[idx]; }
    sh[threadIdx.x] = s;
    __syncthreads();
    for (int off = 128; off > 0; off >>= 1) {
        if (threadIdx.x < off) sh[threadIdx.x] += sh[threadIdx.x + off];
        __syncthreads();
    }
    if (threadIdx.x == 0) bsum[blockIdx.x] = sh[0];
}

__global__ void scan2_kernel(int* __restrict__ bsum, int nb, int* __restrict__ col_ptr, int n) {
    if (threadIdx.x == 0) {
        int run = 0;
        for (int i = 0; i < nb; ++i) { int v = bsum[i]; bsum[i] = run; run += v; }
        col_ptr[n] = run;
    }
}

__global__ void scan3_kernel(const int* __restrict__ cnt, int n, const int* __restrict__ bsum,
                             int* __restrict__ col_ptr) {
    __shared__ int sh[256];
    int base = blockIdx.x * 2048 + threadIdx.x * 8;
    int v[8];
    int s = 0;
#pragma unroll
    for (int i = 0; i < 8; ++i) {
        int idx = base + i;
        v[i] = (idx < n) ? cnt[idx] : 0;
        s += v[i];
    }
    sh[threadIdx.x] = s;
    __syncthreads();
    for (int off = 1; off < 256; off <<= 1) {
        int t = (threadIdx.x >= off) ? sh[threadIdx.x - off] : 0;
        __syncthreads();
        sh[threadIdx.x] += t;
        __syncthreads();
    }
    int run = bsum[blockIdx.x] + sh[threadIdx.x] - s;
#pragma unroll
    for (int i = 0; i < 8; ++i) {
        int idx = base + i;
        if (idx < n) col_ptr[idx] = run;
        run += v[i];
    }
}

__global__ void fill_kernel(const int* __restrict__ row, const int* __restrict__ col,
                            const float* __restrict__ dis, const int* __restrict__ col_ptr,
                            int* __restrict__ fcnt, int* __restrict__ csr_row,
                            float* __restrict__ csr_norm, int E) {
    int e = blockIdx.x * blockDim.x + threadIdx.x;
    if (e < E) {
        int r = row[e], c = col[e];
        int pos = col_ptr[c] + atomicAdd(&fcnt[c], 1);
        csr_row[pos] = r;
        csr_norm[pos] = dis[r] * dis[c];
    }
}

// ---------------- conversions ----------------

__global__ void xcvt_kernel(const float* __restrict__ x, unsigned int* __restrict__ x16, int total4) {
    // total4 = N*128/4 ; each thread converts 4 floats -> 2 packed uints
    for (int i = blockIdx.x * blockDim.x + threadIdx.x; i < total4; i += gridDim.x * blockDim.x) {
        float4 f = ((const float4*)x)[i];
        x16[i * 2] = packbf2(f.x, f.y);
        x16[i * 2 + 1] = packbf2(f.z, f.w);
    }
}

// W1,W2 [128k x 128c] fp32 -> transposed bf16 [c][k]
__global__ void wcvt_kernel(const float* __restrict__ W1, const float* __restrict__ W2,
                            unsigned short* __restrict__ W1t, unsigned short* __restrict__ W2t) {
    int i = blockIdx.x * blockDim.x + threadIdx.x;
    if (i < 32768) {
        const float* W = (i < 16384) ? W1 : W2;
        unsigned short* T = (i < 16384) ? W1t : W2t;
        int j = i & 16383;
        int k = j >> 7, c = j & 127;
        T[c * 128 + k] = bf16rn(W[j]);
    }
}

// ---------------- SpMM (pull, wave per dest node, bf16 rows, fp32 accum) ----------------

template <bool AFF>
__global__ void spmm16_kernel(const int* __restrict__ col_ptr, const int* __restrict__ csr_row,
                              const float* __restrict__ csr_norm,
                              const unsigned short* __restrict__ h_in,
                              const float* __restrict__ scale, const float* __restrict__ shift,
                              unsigned short* __restrict__ h_out, int n) {
    int gw = (blockIdx.x * blockDim.x + threadIdx.x) >> 6;
    int lane = threadIdx.x & 63;
    if (gw >= n) return;
    int beg = col_ptr[gw], end = col_ptr[gw + 1];
    float2 acc = {0.f, 0.f};
    float2 sc, sh;
    if (AFF) {
        sc = ((const float2*)scale)[lane];
        sh = ((const float2*)shift)[lane];
    }
    for (int j = beg; j < end; ++j) {
        int src = csr_row[j];
        float w = csr_norm[j];
        unsigned int u = ((const unsigned int*)(h_in + (size_t)src * 128))[lane];
        float f0 = bflo(u), f1 = bfhi(u);
        if (AFF) {
            f0 = fmaf(sc.x, f0, sh.x);
            f1 = fmaf(sc.y, f1, sh.y);
        }
        acc.x = fmaf(w, f0, acc.x);
        acc.y = fmaf(w, f1, acc.y);
    }
    ((unsigned int*)(h_out + (size_t)gw * 128))[lane] = packbf2(acc.x, acc.y);
}

// ---------------- MFMA GEMM  Y[n, NCT*16] = X[n,128]bf16 @ Wt + bias ----------------
// Wt: [NCT*16 cols][128 k] bf16 (pre-transposed). LDS-staged with XOR swizzle.
// mfma_f32_16x16x32_bf16: A lane: row=l&15, k=(l>>4)*8+j ; B lane: col=l&15, k=(l>>4)*8+j
// D lane: col=l&15, row=(l>>4)*4+i   [verified layouts]

template <int NCT, bool OUTF32>
__launch_bounds__(256)
__global__ void gemm16_kernel(const unsigned short* __restrict__ X,
                              const unsigned short* __restrict__ Wt,
                              const float* __restrict__ bias, void* __restrict__ Y, int n) {
    __shared__ __align__(16) char lds[NCT * 16 * 256];
    // stage Wt -> LDS, 16B chunks, swizzle kbyte ^= (col&7)<<4
    for (int i = threadIdx.x; i < NCT * 16 * 16; i += 256) {
        int col = i >> 4;
        int kbyte = (i & 15) << 4;
        *(uint4*)(lds + col * 256 + (kbyte ^ ((col & 7) << 4))) = ((const uint4*)Wt)[i];
    }
    __syncthreads();

    int lane = threadIdx.x & 63;
    int wave = threadIdx.x >> 6;
    int cl = lane & 15, g = lane >> 4;

    bf16x8 b[NCT][4];
#pragma unroll
    for (int ct = 0; ct < NCT; ++ct) {
        int col = ct * 16 + cl;
#pragma unroll
        for (int kc = 0; kc < 4; ++kc) {
            int kbyte = kc * 64 + g * 16;
            b[ct][kc] = *(const bf16x8*)(lds + col * 256 + (kbyte ^ ((col & 7) << 4)));
        }
    }
    float bc[NCT];
#pragma unroll
    for (int ct = 0; ct < NCT; ++ct) bc[ct] = bias[ct * 16 + cl];

    for (int rb0 = blockIdx.x * 64; rb0 < n; rb0 += gridDim.x * 64) {
        int rb = rb0 + wave * 16;
        if (rb >= n) continue;  // no barriers below: safe
        int row = rb + cl;
        int rowc = row < n ? row : n - 1;
        const unsigned short* xr = X + (size_t)rowc * 128;
        bf16x8 a[4];
#pragma unroll
        for (int kc = 0; kc < 4; ++kc) a[kc] = *(const bf16x8*)(xr + kc * 32 + g * 8);
#pragma unroll
        for (int ct = 0; ct < NCT; ++ct) {
            f32x4 acc = {bc[ct], bc[ct], bc[ct], bc[ct]};
#pragma unroll
            for (int kc = 0; kc < 4; ++kc)
                acc = __builtin_amdgcn_mfma_f32_16x16x32_bf16(a[kc], b[ct][kc], acc, 0, 0, 0);
            int colo = ct * 16 + cl;
#pragma unroll
            for (int i = 0; i < 4; ++i) {
                int ro = rb + g * 4 + i;
                if (ro < n) {
                    if (OUTF32)
                        ((float*)Y)[(size_t)ro * (NCT * 16) + colo] = acc[i];
                    else
                        ((unsigned short*)Y)[(size_t)ro * 128 + colo] = bf16rn(acc[i]);
                }
            }
        }
    }
}

// ---------------- BN stats / finalize / W3 fold ----------------

__global__ void stats16_kernel(const unsigned short* __restrict__ Y, int n,
                               float* __restrict__ gsum, float* __restrict__ gsq) {
    __shared__ float2 ssum[256], ssq[256];
    int c2 = threadIdx.x & 63;
    int g = threadIdx.x >> 6;
    float2 sum = {0.f, 0.f}, sq = {0.f, 0.f};
    for (int r = blockIdx.x * 4 + g; r < n; r += gridDim.x * 4) {
        unsigned int u = ((const unsigned int*)(Y + (size_t)r * 128))[c2];
        float f0 = bflo(u), f1 = bfhi(u);
        sum.x += f0; sum.y += f1;
        sq.x += f0 * f0; sq.y += f1 * f1;
    }
    ssum[threadIdx.x] = sum;
    ssq[threadIdx.x] = sq;
    __syncthreads();
    if (g == 0) {
#pragma unroll
        for (int k = 1; k < 4; ++k) {
            sum.x += ssum[c2 + 64 * k].x; sum.y += ssum[c2 + 64 * k].y;
            sq.x += ssq[c2 + 64 * k].x;   sq.y += ssq[c2 + 64 * k].y;
        }
        atomicAdd(&gsum[2 * c2], sum.x);
        atomicAdd(&gsum[2 * c2 + 1], sum.y);
        atomicAdd(&gsq[2 * c2], sq.x);
        atomicAdd(&gsq[2 * c2 + 1], sq.y);
    }
}

__global__ void bn_final_kernel(const float* __restrict__ gsum, const float* __restrict__ gsq,
                                const float* __restrict__ gamma, const float* __restrict__ beta,
                                int n, float* __restrict__ scale, float* __restrict__ shift) {
    int c = threadIdx.x;
    if (c < 128) {
        float fn = (float)n;
        float mu = gsum[c] / fn;
        float var = gsq[c] / fn - mu * mu;
        float inv = rsqrtf(var + 1e-5f);
        float sc = gamma[c] * inv;
        scale[c] = sc;
        shift[c] = beta[c] - sc * mu;
    }
}

// W3t16[c][k] = bf16(scale2[k]*W3[k][c]);  b3f[c] = b3[c] + sum_k shift2[k]*W3[k][c]
__global__ void fold_w3_kernel(const float* __restrict__ W3, const float* __restrict__ b3,
                               const float* __restrict__ scale, const float* __restrict__ shift,
                               unsigned short* __restrict__ W3t, float* __restrict__ b3f) {
    int c = threadIdx.x;
    if (c < 64) {
        float acc = b3[c];
        for (int k = 0; k < 128; ++k) {
            float w = W3[k * 64 + c];
            W3t[c * 128 + k] = bf16rn(scale[k] * w);
            acc += shift[k] * w;
        }
        b3f[c] = acc;
    }
}

// ---------------- launch ----------------

extern "C" void kernel_launch(void* const* d_in, const int* in_sizes, int n_in,
                              void* d_out, int out_size, void* d_ws, size_t ws_size,
                              hipStream_t stream) {
    const float* x = (const float*)d_in[0];
    const int* edge = (const int*)d_in[1];
    const float* W1 = (const float*)d_in[2];
    const float* b1 = (const float*)d_in[3];
    const float* g1 = (const float*)d_in[4];
    const float* be1 = (const float*)d_in[5];
    const float* W2 = (const float*)d_in[6];
    const float* b2 = (const float*)d_in[7];
    const float* g2 = (const float*)d_in[8];
    const float* be2 = (const float*)d_in[9];
    const float* W3 = (const float*)d_in[10];
    const float* b3 = (const float*)d_in[11];
    float* out = (float*)d_out;

    const int N = in_sizes[0] / 128;
    const int E = in_sizes[1] / 2;
    const int* erow = edge;
    const int* ecol = edge + E;

    char* p = (char*)d_ws;
    size_t off = 0;
    auto carve = [&](size_t bytes) {
        void* r = p + off;
        off += align256(bytes);
        return r;
    };
    unsigned short* x16 = (unsigned short*)carve((size_t)N * 128 * 2);
    unsigned short* A16 = (unsigned short*)carve((size_t)N * 128 * 2);
    unsigned short* B16 = (unsigned short*)carve((size_t)N * 128 * 2);
    int* csr_row = (int*)carve((size_t)E * 4);
    float* csr_norm = (float*)carve((size_t)E * 4);
    int* col_ptr = (int*)carve((size_t)(N + 1) * 4);
    size_t cnt_bytes = align256((size_t)N * 4);
    char* cnt_base = (char*)carve(3 * cnt_bytes);
    int* cnt_row = (int*)cnt_base;
    int* cnt_col = (int*)(cnt_base + cnt_bytes);
    int* fcnt = (int*)(cnt_base + 2 * cnt_bytes);
    float* dis = (float*)carve((size_t)N * 4);
    int* bsum = (int*)carve(4096);
    float* gsum = (float*)carve(1024);
    float* gsq = (float*)(gsum + 128);
    float* scale1 = (float*)carve(512);
    float* shift1 = (float*)carve(512);
    float* scale2 = (float*)carve(512);
    float* shift2 = (float*)carve(512);
    unsigned short* W1t = (unsigned short*)carve(128 * 128 * 2);
    unsigned short* W2t = (unsigned short*)carve(128 * 128 * 2);
    unsigned short* W3t = (unsigned short*)carve(64 * 128 * 2);
    float* b3f = (float*)carve(256);
    (void)ws_size;

    const int TB = 256;
    const int gE = (E + TB - 1) / TB;
    const int gN = (N + TB - 1) / TB;
    const int NBLK = (N + 2047) / 2048;
    const int gSp = (N + 3) / 4;            // 4 waves (dest nodes) per block
    const int gGemm = (N + 63) / 64;        // 64 rows per block

    // --- graph structure ---
    hipMemsetAsync(cnt_base, 0, 3 * cnt_bytes, stream);
    count_kernel<<<gE, TB, 0, stream>>>(erow, ecol, cnt_row, cnt_col, E);
    dis_kernel<<<gN, TB, 0, stream>>>(cnt_row, dis, N);
    scan1_kernel<<<NBLK, TB, 0, stream>>>(cnt_col, N, bsum);
    scan2_kernel<<<1, 64, 0, stream>>>(bsum, NBLK, col_ptr, N);
    scan3_kernel<<<NBLK, TB, 0, stream>>>(cnt_col, N, bsum, col_ptr);
    fill_kernel<<<gE, TB, 0, stream>>>(erow, ecol, dis, col_ptr, fcnt, csr_row, csr_norm, E);

    // --- conversions ---
    xcvt_kernel<<<2048, TB, 0, stream>>>(x, (unsigned int*)x16, N * 32);
    wcvt_kernel<<<128, TB, 0, stream>>>(W1, W2, W1t, W2t);

    // --- h = A^2 x ---
    spmm16_kernel<false><<<gSp, TB, 0, stream>>>(col_ptr, csr_row, csr_norm, x16, nullptr, nullptr, A16, N);
    spmm16_kernel<false><<<gSp, TB, 0, stream>>>(col_ptr, csr_row, csr_norm, A16, nullptr, nullptr, B16, N);

    // --- Y1 = h W1 + b1 (bf16) ; BN1 stats ---
    gemm16_kernel<8, false><<<gGemm, TB, 0, stream>>>(B16, W1t, b1, A16, N);
    hipMemsetAsync(gsum, 0, 1024, stream);
    stats16_kernel<<<256, TB, 0, stream>>>(A16, N, gsum, gsq);
    bn_final_kernel<<<1, 128, 0, stream>>>(gsum, gsq, g1, be1, N, scale1, shift1);

    // --- h = A^2 BN1(Y1) (affine fused into first gather) ---
    spmm16_kernel<true><<<gSp, TB, 0, stream>>>(col_ptr, csr_row, csr_norm, A16, scale1, shift1, B16, N);
    spmm16_kernel<false><<<gSp, TB, 0, stream>>>(col_ptr, csr_row, csr_norm, B16, nullptr, nullptr, A16, N);

    // --- Y2 = h W2 + b2 (bf16) ; BN2 stats ---
    gemm16_kernel<8, false><<<gGemm, TB, 0, stream>>>(A16, W2t, b2, B16, N);
    hipMemsetAsync(gsum, 0, 1024, stream);
    stats16_kernel<<<256, TB, 0, stream>>>(B16, N, gsum, gsq);
    bn_final_kernel<<<1, 128, 0, stream>>>(gsum, gsq, g2, be2, N, scale2, shift2);

    // --- out = BN2(Y2) W3 + b3, BN2 folded into W3/b3 ---
    fold_w3_kernel<<<1, 64, 0, stream>>>(W3, b3, scale2, shift2, W3t, b3f);
    gemm16_kernel<4, true><<<gGemm, TB, 0, stream>>>(B16, W3t, b3f, out, N);
}

// Round 3
// 619.370 us; speedup vs baseline: 2.1778x; 1.5722x over previous
//
#include <hip/hip_runtime.h>

// SGCNet bf16 pipeline: CSR build -> spmm(bf16 gather, fp32 acc, 8-deep MLP) x4
// -> MFMA bf16 GEMMs with BN folding.  Output fp32.

typedef __attribute__((ext_vector_type(8))) short bf16x8;
typedef __attribute__((ext_vector_type(4))) float f32x4;

static inline size_t align256(size_t x) { return (x + 255) & ~(size_t)255; }

__device__ inline unsigned short bf16rn(float f) {
    unsigned int u = __builtin_bit_cast(unsigned int, f);
    u += 0x7fffu + ((u >> 16) & 1u);
    return (unsigned short)(u >> 16);
}
__device__ inline float bflo(unsigned int u) { return __builtin_bit_cast(float, u << 16); }
__device__ inline float bfhi(unsigned int u) { return __builtin_bit_cast(float, u & 0xffff0000u); }
__device__ inline unsigned int packbf2(float a, float b) {
    return (unsigned int)bf16rn(a) | ((unsigned int)bf16rn(b) << 16);
}

// ---------------- CSR build ----------------

__global__ void count_kernel(const int* __restrict__ row, const int* __restrict__ col,
                             int* __restrict__ cnt_row, int* __restrict__ cnt_col, int E) {
    int e = blockIdx.x * blockDim.x + threadIdx.x;
    if (e < E) {
        atomicAdd(&cnt_row[row[e]], 1);
        atomicAdd(&cnt_col[col[e]], 1);
    }
}

__global__ void dis_kernel(const int* __restrict__ cnt_row, float* __restrict__ dis, int n) {
    int i = blockIdx.x * blockDim.x + threadIdx.x;
    if (i < n) {
        int d = cnt_row[i];
        dis[i] = d > 0 ? rsqrtf((float)d) : 0.f;
    }
}

__global__ void scan1_kernel(const int* __restrict__ cnt, int n, int* __restrict__ bsum) {
    __shared__ int sh[256];
    int base = blockIdx.x * 2048 + threadIdx.x * 8;
    int s = 0;
#pragma unroll
    for (int i = 0; i < 8; ++i) { int idx = base + i; if (idx < n) s += cnt[idx]; }
    sh[threadIdx.x] = s;
    __syncthreads();
    for (int off = 128; off > 0; off >>= 1) {
        if (threadIdx.x < off) sh[threadIdx.x] += sh[threadIdx.x + off];
        __syncthreads();
    }
    if (threadIdx.x == 0) bsum[blockIdx.x] = sh[0];
}

__global__ void scan2_kernel(int* __restrict__ bsum, int nb, int* __restrict__ col_ptr, int n) {
    if (threadIdx.x == 0) {
        int run = 0;
        for (int i = 0; i < nb; ++i) { int v = bsum[i]; bsum[i] = run; run += v; }
        col_ptr[n] = run;
    }
}

__global__ void scan3_kernel(const int* __restrict__ cnt, int n, const int* __restrict__ bsum,
                             int* __restrict__ col_ptr) {
    __shared__ int sh[256];
    int base = blockIdx.x * 2048 + threadIdx.x * 8;
    int v[8];
    int s = 0;
#pragma unroll
    for (int i = 0; i < 8; ++i) {
        int idx = base + i;
        v[i] = (idx < n) ? cnt[idx] : 0;
        s += v[i];
    }
    sh[threadIdx.x] = s;
    __syncthreads();
    for (int off = 1; off < 256; off <<= 1) {
        int t = (threadIdx.x >= off) ? sh[threadIdx.x - off] : 0;
        __syncthreads();
        sh[threadIdx.x] += t;
        __syncthreads();
    }
    int run = bsum[blockIdx.x] + sh[threadIdx.x] - s;
#pragma unroll
    for (int i = 0; i < 8; ++i) {
        int idx = base + i;
        if (idx < n) col_ptr[idx] = run;
        run += v[i];
    }
}

__global__ void fill_kernel(const int* __restrict__ row, const int* __restrict__ col,
                            const float* __restrict__ dis, const int* __restrict__ col_ptr,
                            int* __restrict__ fcnt, int* __restrict__ csr_row,
                            float* __restrict__ csr_norm, int E) {
    int e = blockIdx.x * blockDim.x + threadIdx.x;
    if (e < E) {
        int r = row[e], c = col[e];
        int pos = col_ptr[c] + atomicAdd(&fcnt[c], 1);
        csr_row[pos] = r;
        csr_norm[pos] = dis[r] * dis[c];
    }
}

// ---------------- conversions ----------------

__global__ void xcvt_kernel(const float* __restrict__ x, unsigned int* __restrict__ x16, int total4) {
    for (int i = blockIdx.x * blockDim.x + threadIdx.x; i < total4; i += gridDim.x * blockDim.x) {
        float4 f = ((const float4*)x)[i];
        x16[i * 2] = packbf2(f.x, f.y);
        x16[i * 2 + 1] = packbf2(f.z, f.w);
    }
}

// W1,W2 [128k x 128c] fp32 -> transposed bf16 [c][k]
__global__ void wcvt_kernel(const float* __restrict__ W1, const float* __restrict__ W2,
                            unsigned short* __restrict__ W1t, unsigned short* __restrict__ W2t) {
    int i = blockIdx.x * blockDim.x + threadIdx.x;
    if (i < 32768) {
        const float* W = (i < 16384) ? W1 : W2;
        unsigned short* T = (i < 16384) ? W1t : W2t;
        int j = i & 16383;
        int k = j >> 7, c = j & 127;
        T[c * 128 + k] = bf16rn(W[j]);
    }
}

// ---------------- SpMM (pull, wave per dest node, bf16 rows, 8-deep MLP) ----------------

template <bool AFF>
__global__ void spmm16_kernel(const int* __restrict__ col_ptr, const int* __restrict__ csr_row,
                              const float* __restrict__ csr_norm,
                              const unsigned short* __restrict__ h_in,
                              const float* __restrict__ scale, const float* __restrict__ shift,
                              unsigned short* __restrict__ h_out, int n) {
    int gw = (blockIdx.x * blockDim.x + threadIdx.x) >> 6;
    int lane = threadIdx.x & 63;
    if (gw >= n) return;
    int beg = col_ptr[gw], end = col_ptr[gw + 1];
    unsigned int* outp = (unsigned int*)(h_out + (size_t)gw * 128) + lane;
    if (beg == end) {
        *outp = 0u;
        return;
    }
    float2 acc = {0.f, 0.f};
    float2 sc, sh;
    if (AFF) {
        sc = ((const float2*)scale)[lane];
        sh = ((const float2*)shift)[lane];
    }
    for (int j0 = beg; j0 < end; j0 += 8) {
        int idx[8];
        float w[8];
#pragma unroll
        for (int k = 0; k < 8; ++k) {
            int j = j0 + k;
            bool v = j < end;
            idx[k] = v ? csr_row[j] : csr_row[beg];
            w[k] = v ? csr_norm[j] : 0.f;
        }
        unsigned int u[8];
#pragma unroll
        for (int k = 0; k < 8; ++k)
            u[k] = ((const unsigned int*)(h_in + (size_t)idx[k] * 128))[lane];
#pragma unroll
        for (int k = 0; k < 8; ++k) {
            float f0 = bflo(u[k]), f1 = bfhi(u[k]);
            if (AFF) {
                f0 = fmaf(sc.x, f0, sh.x);
                f1 = fmaf(sc.y, f1, sh.y);
            }
            acc.x = fmaf(w[k], f0, acc.x);
            acc.y = fmaf(w[k], f1, acc.y);
        }
    }
    *outp = packbf2(acc.x, acc.y);
}

// ---------------- MFMA GEMM  Y[n, NCT*16] = X[n,128]bf16 @ Wt + bias ----------------

template <int NCT, bool OUTF32>
__launch_bounds__(256)
__global__ void gemm16_kernel(const unsigned short* __restrict__ X,
                              const unsigned short* __restrict__ Wt,
                              const float* __restrict__ bias, void* __restrict__ Y, int n) {
    __shared__ __align__(16) char lds[NCT * 16 * 256];
    for (int i = threadIdx.x; i < NCT * 16 * 16; i += 256) {
        int col = i >> 4;
        int kbyte = (i & 15) << 4;
        *(uint4*)(lds + col * 256 + (kbyte ^ ((col & 7) << 4))) = ((const uint4*)Wt)[i];
    }
    __syncthreads();

    int lane = threadIdx.x & 63;
    int wave = threadIdx.x >> 6;
    int cl = lane & 15, g = lane >> 4;

    bf16x8 b[NCT][4];
#pragma unroll
    for (int ct = 0; ct < NCT; ++ct) {
        int col = ct * 16 + cl;
#pragma unroll
        for (int kc = 0; kc < 4; ++kc) {
            int kbyte = kc * 64 + g * 16;
            b[ct][kc] = *(const bf16x8*)(lds + col * 256 + (kbyte ^ ((col & 7) << 4)));
        }
    }
    float bc[NCT];
#pragma unroll
    for (int ct = 0; ct < NCT; ++ct) bc[ct] = bias[ct * 16 + cl];

    for (int rb0 = blockIdx.x * 64; rb0 < n; rb0 += gridDim.x * 64) {
        int rb = rb0 + wave * 16;
        if (rb >= n) continue;
        int row = rb + cl;
        int rowc = row < n ? row : n - 1;
        const unsigned short* xr = X + (size_t)rowc * 128;
        bf16x8 a[4];
#pragma unroll
        for (int kc = 0; kc < 4; ++kc) a[kc] = *(const bf16x8*)(xr + kc * 32 + g * 8);
#pragma unroll
        for (int ct = 0; ct < NCT; ++ct) {
            f32x4 acc = {bc[ct], bc[ct], bc[ct], bc[ct]};
#pragma unroll
            for (int kc = 0; kc < 4; ++kc)
                acc = __builtin_amdgcn_mfma_f32_16x16x32_bf16(a[kc], b[ct][kc], acc, 0, 0, 0);
            int colo = ct * 16 + cl;
#pragma unroll
            for (int i = 0; i < 4; ++i) {
                int ro = rb + g * 4 + i;
                if (ro < n) {
                    if (OUTF32)
                        ((float*)Y)[(size_t)ro * (NCT * 16) + colo] = acc[i];
                    else
                        ((unsigned short*)Y)[(size_t)ro * 128 + colo] = bf16rn(acc[i]);
                }
            }
        }
    }
}

// ---------------- BN stats / finalize / W3 fold ----------------

__global__ void stats16_kernel(const unsigned short* __restrict__ Y, int n,
                               float* __restrict__ gsum, float* __restrict__ gsq) {
    __shared__ float2 ssum[256], ssq[256];
    int c2 = threadIdx.x & 63;
    int g = threadIdx.x >> 6;
    float2 sum = {0.f, 0.f}, sq = {0.f, 0.f};
    for (int r = blockIdx.x * 4 + g; r < n; r += gridDim.x * 4) {
        unsigned int u = ((const unsigned int*)(Y + (size_t)r * 128))[c2];
        float f0 = bflo(u), f1 = bfhi(u);
        sum.x += f0; sum.y += f1;
        sq.x += f0 * f0; sq.y += f1 * f1;
    }
    ssum[threadIdx.x] = sum;
    ssq[threadIdx.x] = sq;
    __syncthreads();
    if (g == 0) {
#pragma unroll
        for (int k = 1; k < 4; ++k) {
            sum.x += ssum[c2 + 64 * k].x; sum.y += ssum[c2 + 64 * k].y;
            sq.x += ssq[c2 + 64 * k].x;   sq.y += ssq[c2 + 64 * k].y;
        }
        atomicAdd(&gsum[2 * c2], sum.x);
        atomicAdd(&gsum[2 * c2 + 1], sum.y);
        atomicAdd(&gsq[2 * c2], sq.x);
        atomicAdd(&gsq[2 * c2 + 1], sq.y);
    }
}

__global__ void bn_final_kernel(const float* __restrict__ gsum, const float* __restrict__ gsq,
                                const float* __restrict__ gamma, const float* __restrict__ beta,
                                int n, float* __restrict__ scale, float* __restrict__ shift) {
    int c = threadIdx.x;
    if (c < 128) {
        float fn = (float)n;
        float mu = gsum[c] / fn;
        float var = gsq[c] / fn - mu * mu;
        float inv = rsqrtf(var + 1e-5f);
        float sc = gamma[c] * inv;
        scale[c] = sc;
        shift[c] = beta[c] - sc * mu;
    }
}

__global__ void fold_w3_kernel(const float* __restrict__ W3, const float* __restrict__ b3,
                               const float* __restrict__ scale, const float* __restrict__ shift,
                               unsigned short* __restrict__ W3t, float* __restrict__ b3f) {
    int c = threadIdx.x;
    if (c < 64) {
        float acc = b3[c];
        for (int k = 0; k < 128; ++k) {
            float w = W3[k * 64 + c];
            W3t[c * 128 + k] = bf16rn(scale[k] * w);
            acc += shift[k] * w;
        }
        b3f[c] = acc;
    }
}

// ---------------- launch ----------------

extern "C" void kernel_launch(void* const* d_in, const int* in_sizes, int n_in,
                              void* d_out, int out_size, void* d_ws, size_t ws_size,
                              hipStream_t stream) {
    const float* x = (const float*)d_in[0];
    const int* edge = (const int*)d_in[1];
    const float* W1 = (const float*)d_in[2];
    const float* b1 = (const float*)d_in[3];
    const float* g1 = (const float*)d_in[4];
    const float* be1 = (const float*)d_in[5];
    const float* W2 = (const float*)d_in[6];
    const float* b2 = (const float*)d_in[7];
    const float* g2 = (const float*)d_in[8];
    const float* be2 = (const float*)d_in[9];
    const float* W3 = (const float*)d_in[10];
    const float* b3 = (const float*)d_in[11];
    float* out = (float*)d_out;

    const int N = in_sizes[0] / 128;
    const int E = in_sizes[1] / 2;
    const int* erow = edge;
    const int* ecol = edge + E;

    char* p = (char*)d_ws;
    size_t off = 0;
    auto carve = [&](size_t bytes) {
        void* r = p + off;
        off += align256(bytes);
        return r;
    };
    unsigned short* x16 = (unsigned short*)carve((size_t)N * 128 * 2);
    unsigned short* A16 = (unsigned short*)carve((size_t)N * 128 * 2);
    unsigned short* B16 = (unsigned short*)carve((size_t)N * 128 * 2);
    int* csr_row = (int*)carve((size_t)E * 4);
    float* csr_norm = (float*)carve((size_t)E * 4);
    int* col_ptr = (int*)carve((size_t)(N + 1) * 4);
    size_t cnt_bytes = align256((size_t)N * 4);
    char* cnt_base = (char*)carve(3 * cnt_bytes);
    int* cnt_row = (int*)cnt_base;
    int* cnt_col = (int*)(cnt_base + cnt_bytes);
    int* fcnt = (int*)(cnt_base + 2 * cnt_bytes);
    float* dis = (float*)carve((size_t)N * 4);
    int* bsum = (int*)carve(4096);
    float* gsum = (float*)carve(1024);
    float* gsq = (float*)(gsum + 128);
    float* scale1 = (float*)carve(512);
    float* shift1 = (float*)carve(512);
    float* scale2 = (float*)carve(512);
    float* shift2 = (float*)carve(512);
    unsigned short* W1t = (unsigned short*)carve(128 * 128 * 2);
    unsigned short* W2t = (unsigned short*)carve(128 * 128 * 2);
    unsigned short* W3t = (unsigned short*)carve(64 * 128 * 2);
    float* b3f = (float*)carve(256);
    (void)ws_size;

    const int TB = 256;
    const int gE = (E + TB - 1) / TB;
    const int gN = (N + TB - 1) / TB;
    const int NBLK = (N + 2047) / 2048;
    const int gSp = (N + 3) / 4;
    const int gGemm = (N + 63) / 64;

    // --- graph structure ---
    hipMemsetAsync(cnt_base, 0, 3 * cnt_bytes, stream);
    count_kernel<<<gE, TB, 0, stream>>>(erow, ecol, cnt_row, cnt_col, E);
    dis_kernel<<<gN, TB, 0, stream>>>(cnt_row, dis, N);
    scan1_kernel<<<NBLK, TB, 0, stream>>>(cnt_col, N, bsum);
    scan2_kernel<<<1, 64, 0, stream>>>(bsum, NBLK, col_ptr, N);
    scan3_kernel<<<NBLK, TB, 0, stream>>>(cnt_col, N, bsum, col_ptr);
    fill_kernel<<<gE, TB, 0, stream>>>(erow, ecol, dis, col_ptr, fcnt, csr_row, csr_norm, E);

    // --- conversions ---
    xcvt_kernel<<<2048, TB, 0, stream>>>(x, (unsigned int*)x16, N * 32);
    wcvt_kernel<<<128, TB, 0, stream>>>(W1, W2, W1t, W2t);

    // --- h = A^2 x ---
    spmm16_kernel<false><<<gSp, TB, 0, stream>>>(col_ptr, csr_row, csr_norm, x16, nullptr, nullptr, A16, N);
    spmm16_kernel<false><<<gSp, TB, 0, stream>>>(col_ptr, csr_row, csr_norm, A16, nullptr, nullptr, B16, N);

    // --- Y1 = h W1 + b1 (bf16) ; BN1 stats ---
    gemm16_kernel<8, false><<<gGemm, TB, 0, stream>>>(B16, W1t, b1, A16, N);
    hipMemsetAsync(gsum, 0, 1024, stream);
    stats16_kernel<<<256, TB, 0, stream>>>(A16, N, gsum, gsq);
    bn_final_kernel<<<1, 128, 0, stream>>>(gsum, gsq, g1, be1, N, scale1, shift1);

    // --- h = A^2 BN1(Y1) ---
    spmm16_kernel<true><<<gSp, TB, 0, stream>>>(col_ptr, csr_row, csr_norm, A16, scale1, shift1, B16, N);
    spmm16_kernel<false><<<gSp, TB, 0, stream>>>(col_ptr, csr_row, csr_norm, B16, nullptr, nullptr, A16, N);

    // --- Y2 = h W2 + b2 (bf16) ; BN2 stats ---
    gemm16_kernel<8, false><<<gGemm, TB, 0, stream>>>(A16, W2t, b2, B16, N);
    hipMemsetAsync(gsum, 0, 1024, stream);
    stats16_kernel<<<256, TB, 0, stream>>>(B16, N, gsum, gsq);
    bn_final_kernel<<<1, 128, 0, stream>>>(gsum, gsq, g2, be2, N, scale2, shift2);

    // --- out = BN2(Y2) W3 + b3 ---
    fold_w3_kernel<<<1, 64, 0, stream>>>(W3, b3, scale2, shift2, W3t, b3f);
    gemm16_kernel<4, true><<<gGemm, TB, 0, stream>>>(B16, W3t, b3f, out, N);
}